// Round 1
// baseline (1522.038 us; speedup 1.0000x reference)
//
#include <hip/hip_runtime.h>
#include <stdint.h>

// RPN rotated-NMS post-processor, MI355X. Round 1: correctness-first.
// Pipeline: sigmoid+topk(1000) -> decode -> rotated IoU mask -> greedy NMS -> out [4,1000,6]

#define NBATCH 4
#define AANCH 15
#define HDIM 200
#define WDIM 200
#define MTOT (AANCH*HDIM*WDIM)   // 600000
#define KTOP 1000
#define POSTN 300
#define NBINS 16384
#define CAND_CAP 4096
#define NWORDS 16                // ceil(1000/64)
#define NMS_TH 0.7f

// ---------------- ws layout ----------------
constexpr size_t OFF_HIST = 0;
constexpr size_t SZ_HIST  = (size_t)NBATCH*NBINS*4;                 // 262144
constexpr size_t OFF_CNT  = OFF_HIST + SZ_HIST;
constexpr size_t OFF_THR  = OFF_CNT + 256;
constexpr size_t OFF_CAND = OFF_THR + 256;
constexpr size_t OFF_TOPK = OFF_CAND + (size_t)NBATCH*CAND_CAP*8;
constexpr size_t OFF_PROP = OFF_TOPK + (size_t)NBATCH*KTOP*8;
constexpr size_t OFF_SCORE= OFF_PROP + (size_t)NBATCH*KTOP*5*4;
constexpr size_t OFF_CORN = OFF_SCORE+ (size_t)NBATCH*KTOP*4;
constexpr size_t OFF_AREA = OFF_CORN + (size_t)NBATCH*KTOP*8*4;
constexpr size_t OFF_RAD  = OFF_AREA + (size_t)NBATCH*KTOP*4;
constexpr size_t OFF_VALID= OFF_RAD  + (size_t)NBATCH*KTOP*4;
constexpr size_t OFF_MASK = OFF_VALID+ (size_t)NBATCH*KTOP*4;
constexpr size_t OFF_KEEP = OFF_MASK + (size_t)NBATCH*KTOP*NWORDS*8;

// sigmoid guess #1: XLA LogisticExpander form 1/(1+exp(-x)).
__device__ __forceinline__ float sigmoid_ref(float x) {
  return 1.0f / (1.0f + expf(-x));
}

// load objectness at linear layout position t (coalesced), return (score_bits, flat_idx)
__device__ __forceinline__ void score_at(const float* obj, int t, uint32_t& bits, uint32_t& fidx) {
  int n = t / (AANCH*HDIM*WDIM);
  int rem = t % (AANCH*HDIM*WDIM);
  int hw = rem % (HDIM*WDIM);
  float x = obj[t];
  bits = __float_as_uint(sigmoid_ref(x));
  int a = rem / (HDIM*WDIM);
  fidx = (uint32_t)(hw*AANCH + a);   // flat index in (H,W,A) score space
  (void)n;
}

__global__ void k_hist(const float* __restrict__ obj, uint32_t* __restrict__ hist) {
  int t = blockIdx.x*blockDim.x + threadIdx.x;
  if (t >= NBATCH*MTOT) return;
  int n = t / MTOT;
  uint32_t bits, fidx;
  score_at(obj, t, bits, fidx);
  uint32_t bin = bits >> 16; if (bin > NBINS-1) bin = NBINS-1;
  atomicAdd(&hist[n*NBINS + bin], 1u);
}

__global__ void k_thresh(const uint32_t* __restrict__ hist, uint32_t* __restrict__ thr) {
  int n = blockIdx.x;
  if (threadIdx.x != 0) return;
  uint32_t cum = 0; int b;
  for (b = NBINS-1; b >= 0; --b) { cum += hist[n*NBINS + b]; if (cum >= KTOP) break; }
  thr[n] = (b < 0) ? 0u : (uint32_t)b;
}

__global__ void k_compact(const float* __restrict__ obj, const uint32_t* __restrict__ thr,
                          uint64_t* __restrict__ cand, uint32_t* __restrict__ cnt) {
  int t = blockIdx.x*blockDim.x + threadIdx.x;
  if (t >= NBATCH*MTOT) return;
  int n = t / MTOT;
  uint32_t bits, fidx;
  score_at(obj, t, bits, fidx);
  uint32_t bin = bits >> 16; if (bin > NBINS-1) bin = NBINS-1;
  if (bin >= thr[n]) {
    uint32_t p = atomicAdd(&cnt[n], 1u);
    if (p < CAND_CAP)
      cand[(size_t)n*CAND_CAP + p] = ((uint64_t)bits << 32) | (uint32_t)(~fidx);
  }
}

// one block per batch: bitonic sort CAND_CAP keys ascending, emit top KTOP descending
__global__ void k_sort(const uint64_t* __restrict__ cand, const uint32_t* __restrict__ cnt,
                       uint64_t* __restrict__ topk) {
  __shared__ uint64_t sk[CAND_CAP];
  int n = blockIdx.x, tid = threadIdx.x;
  uint32_t c = cnt[n]; if (c > CAND_CAP) c = CAND_CAP;
  for (int i = tid; i < CAND_CAP; i += blockDim.x)
    sk[i] = (i < (int)c) ? cand[(size_t)n*CAND_CAP + i] : 0ull;
  __syncthreads();
  for (int len = 2; len <= CAND_CAP; len <<= 1) {
    for (int str = len >> 1; str > 0; str >>= 1) {
      for (int i = tid; i < CAND_CAP; i += blockDim.x) {
        int j = i ^ str;
        if (j > i) {
          bool up = ((i & len) == 0);
          uint64_t x = sk[i], y = sk[j];
          if ((x > y) == up) { sk[i] = y; sk[j] = x; }
        }
      }
      __syncthreads();
    }
  }
  for (int k = tid; k < KTOP; k += blockDim.x)
    topk[(size_t)n*KTOP + k] = sk[CAND_CAP-1-k];
}

__global__ void k_decode(const float* __restrict__ breg, const float* __restrict__ anch,
                         const uint64_t* __restrict__ topk,
                         float* __restrict__ prop, float* __restrict__ score,
                         float* __restrict__ corn, float* __restrict__ area,
                         float* __restrict__ rad, uint32_t* __restrict__ validf) {
#pragma clang fp contract(off)
  int t = blockIdx.x*blockDim.x + threadIdx.x;
  if (t >= NBATCH*KTOP) return;
  int n = t / KTOP;
  uint64_t key = topk[t];
  uint32_t idx = ~(uint32_t)(key & 0xFFFFFFFFull);
  float s = __uint_as_float((uint32_t)(key >> 32));
  int a = idx % AANCH, pos = idx / AANCH;
  int w = pos % WDIM, h = pos / WDIM;
  float d[5], an[5];
  #pragma unroll
  for (int j = 0; j < 5; ++j)
    d[j] = breg[((n*(AANCH*5) + (a*5+j))*HDIM + h)*WDIM + w];
  #pragma unroll
  for (int j = 0; j < 5; ++j)
    an[j] = anch[((size_t)n*MTOT + idx)*5 + j];
  const float CLIP = 4.135166556742356f;           // log(1000/16)
  float dw = fminf(d[2], CLIP), dh = fminf(d[3], CLIP);
  float x  = d[0]*an[2] + an[0];
  float y  = d[1]*an[3] + an[1];
  float bw = expf(dw)*an[2];
  float bh = expf(dh)*an[3];
  float th = an[4] + d[4]*57.29577951308232f;      // 180/pi
  prop[t*5+0]=x; prop[t*5+1]=y; prop[t*5+2]=bw; prop[t*5+3]=bh; prop[t*5+4]=th;
  score[t] = s;
  validf[t] = (bw >= 4.0f && bh >= 4.0f) ? 1u : 0u;
  area[t] = bw*bh;
  rad[t]  = 0.5f*sqrtf(bw*bw + bh*bh);
  float ang = th * 0.017453292519943295f;          // pi/180
  float cs = cosf(ang), sn = sinf(ang);
  float hw2 = bw*0.5f, hh2 = bh*0.5f;
  const float sx[4] = {1.f,-1.f,-1.f,1.f};
  const float sy[4] = {1.f,1.f,-1.f,-1.f};
  #pragma unroll
  for (int k = 0; k < 4; ++k) {
    float dxk = sx[k]*hw2, dyk = sy[k]*hh2;
    float cx = (x + cs*dxk) - sn*dyk;
    float cy = (y + sn*dxk) + cs*dyk;
    corn[t*8 + k*2 + 0] = cx;
    corn[t*8 + k*2 + 1] = cy;
  }
}

// Sutherland-Hodgman, mirrors reference _clip_halfplane / _pair_inter_area arithmetic
__device__ float quad_inter_area(const float* __restrict__ ca, const float* __restrict__ cb) {
#pragma clang fp contract(off)
  float px[8], py[8];
  int n = 4;
  #pragma unroll
  for (int i = 0; i < 4; ++i) { px[i] = ca[2*i]; py[i] = ca[2*i+1]; }
  for (int e = 0; e < 4; ++e) {
    float p1x = cb[2*e], p1y = cb[2*e+1];
    int e2 = (e+1)&3;
    float dx = cb[2*e2] - p1x, dy = cb[2*e2+1] - p1y;
    float sd[8];
    for (int i = 0; i < n; ++i)
      sd[i] = dx*(py[i]-p1y) - dy*(px[i]-p1x);
    float qx[8], qy[8];
    int m = 0;
    for (int i = 0; i < n; ++i) {
      int nx = (i+1 < n) ? i+1 : 0;
      bool ini = sd[i] >= 0.0f, inn = sd[nx] >= 0.0f;
      if (ini) { qx[m]=px[i]; qy[m]=py[i]; ++m; }
      if (ini != inn) {
        float den = sd[i]-sd[nx];
        float dd = (fabsf(den) < 1e-12f) ? 1e-12f : den;
        float tt = sd[i]/dd;
        qx[m] = px[i] + tt*(px[nx]-px[i]);
        qy[m] = py[i] + tt*(py[nx]-py[i]);
        ++m;
      }
    }
    n = m;
    for (int i = 0; i < n; ++i) { px[i]=qx[i]; py[i]=qy[i]; }
    if (n == 0) break;
  }
  float ssum = 0.0f;
  for (int i = 0; i < n; ++i) {
    int nx = (i+1 < n) ? i+1 : 0;
    ssum += px[i]*py[nx] - px[nx]*py[i];
  }
  return 0.5f*fabsf(ssum);
}

// each wave computes 64 suppression bits for (batch n, row i, word jb)
__global__ __launch_bounds__(256) void k_mask(const float* __restrict__ prop,
                                              const float* __restrict__ corn,
                                              const float* __restrict__ area,
                                              const float* __restrict__ rad,
                                              uint64_t* __restrict__ mask) {
#pragma clang fp contract(off)
  int gw = blockIdx.x*(blockDim.x>>6) + (threadIdx.x>>6);
  int lane = threadIdx.x & 63;
  if (gw >= NBATCH*KTOP*NWORDS) return;
  int n   = gw / (KTOP*NWORDS);
  int rem = gw % (KTOP*NWORDS);
  int i   = rem / NWORDS;
  int jb  = rem % NWORDS;
  int j   = jb*64 + lane;
  bool sup = false;
  if (j > i && j < KTOP) {
    int bi = n*KTOP + i, bj = n*KTOP + j;
    float dx = prop[bi*5+0] - prop[bj*5+0];
    float dy = prop[bi*5+1] - prop[bj*5+1];
    float d2 = dx*dx + dy*dy;
    float rs = rad[bi] + rad[bj];
    if (d2 <= rs*rs*1.0001f) {
      float inter = quad_inter_area(&corn[(size_t)bi*8], &corn[(size_t)bj*8]);
      float uni = (area[bi] + area[bj]) - inter;
      float iou = inter / fmaxf(uni, 1e-8f);
      sup = iou > NMS_TH;
    }
  }
  unsigned long long w64 = __ballot(sup);
  if (lane == 0) mask[((size_t)n*KTOP + i)*NWORDS + jb] = w64;
}

// one wave per batch: serial greedy NMS over bitmask rows + rank<=300 trim
__global__ void k_nms(const uint32_t* __restrict__ validf, const uint64_t* __restrict__ mask,
                      uint64_t* __restrict__ keep) {
  __shared__ uint64_t kw[NWORDS];
  int n = blockIdx.x, lane = threadIdx.x;
  if (lane < NWORDS) {
    uint64_t wrd = 0;
    for (int b = 0; b < 64; ++b) {
      int k = lane*64 + b;
      if (k < KTOP && validf[n*KTOP + k]) wrd |= (1ull << b);
    }
    kw[lane] = wrd;
  }
  __syncthreads();
  uint64_t mcur = (lane < NWORDS) ? mask[((size_t)n*KTOP + 0)*NWORDS + lane] : 0ull;
  for (int i = 0; i < KTOP; ++i) {
    uint64_t mnext = (i+1 < KTOP && lane < NWORDS)
                     ? mask[((size_t)n*KTOP + (i+1))*NWORDS + lane] : 0ull;
    bool alive = (kw[i>>6] >> (i&63)) & 1ull;
    if (alive && lane < NWORDS) kw[lane] &= ~mcur;
    __syncthreads();
    mcur = mnext;
  }
  if (lane == 0) {
    int prev = 0;
    for (int t = 0; t < NWORDS; ++t) {
      uint64_t wrd = kw[t];
      int pc = __popcll(wrd);
      if (prev >= POSTN) wrd = 0;
      else if (prev + pc > POSTN) {
        int allow = POSTN - prev;
        while (__popcll(wrd) > allow) wrd &= ~(1ull << (63 - __clzll(wrd)));
      }
      prev += __popcll(wrd);
      keep[n*NWORDS + t] = wrd;
    }
  }
}

__global__ void k_out(const float* __restrict__ prop, const float* __restrict__ score,
                      const uint64_t* __restrict__ keep, float* __restrict__ out) {
  int t = blockIdx.x*blockDim.x + threadIdx.x;
  if (t >= NBATCH*KTOP) return;
  int n = t / KTOP, k = t % KTOP;
  bool b = (keep[n*NWORDS + (k>>6)] >> (k&63)) & 1ull;
  float f = b ? 1.0f : 0.0f;
  #pragma unroll
  for (int c = 0; c < 5; ++c) out[t*6 + c] = prop[t*5 + c] * f;
  out[t*6 + 5] = score[t] * f;
}

extern "C" void kernel_launch(void* const* d_in, const int* in_sizes, int n_in,
                              void* d_out, int out_size, void* d_ws, size_t ws_size,
                              hipStream_t stream) {
  const float* obj  = (const float*)d_in[0];
  const float* breg = (const float*)d_in[1];
  const float* anch = (const float*)d_in[2];
  float* out = (float*)d_out;
  char* ws = (char*)d_ws;

  uint32_t* hist  = (uint32_t*)(ws + OFF_HIST);
  uint32_t* cnt   = (uint32_t*)(ws + OFF_CNT);
  uint32_t* thr   = (uint32_t*)(ws + OFF_THR);
  uint64_t* cand  = (uint64_t*)(ws + OFF_CAND);
  uint64_t* topk  = (uint64_t*)(ws + OFF_TOPK);
  float*    prop  = (float*)(ws + OFF_PROP);
  float*    score = (float*)(ws + OFF_SCORE);
  float*    corn  = (float*)(ws + OFF_CORN);
  float*    area  = (float*)(ws + OFF_AREA);
  float*    rad   = (float*)(ws + OFF_RAD);
  uint32_t* validf= (uint32_t*)(ws + OFF_VALID);
  uint64_t* mask  = (uint64_t*)(ws + OFF_MASK);
  uint64_t* keep  = (uint64_t*)(ws + OFF_KEEP);

  hipMemsetAsync(ws, 0, OFF_THR, stream);   // zero hist + cand counters

  int nt = NBATCH*MTOT;
  k_hist   <<<(nt+255)/256, 256, 0, stream>>>(obj, hist);
  k_thresh <<<NBATCH, 64, 0, stream>>>(hist, thr);
  k_compact<<<(nt+255)/256, 256, 0, stream>>>(obj, thr, cand, cnt);
  k_sort   <<<NBATCH, 256, 0, stream>>>(cand, cnt, topk);
  k_decode <<<(NBATCH*KTOP+255)/256, 256, 0, stream>>>(breg, anch, topk, prop, score, corn, area, rad, validf);
  k_mask   <<<NBATCH*KTOP*NWORDS/4, 256, 0, stream>>>(prop, corn, area, rad, mask);
  k_nms    <<<NBATCH, 64, 0, stream>>>(validf, mask, keep);
  k_out    <<<(NBATCH*KTOP+255)/256, 256, 0, stream>>>(prop, score, keep, out);
}

// Round 2
// 491.682 us; speedup vs baseline: 3.0956x; 3.0956x over previous
//
#include <hip/hip_runtime.h>
#include <stdint.h>

// RPN rotated-NMS post-processor, MI355X. Round 2: LDS-privatized histogram,
// parallel threshold scan, LDS-resident NMS mask, wider bitonic sort.

#define NBATCH 4
#define AANCH 15
#define HDIM 200
#define WDIM 200
#define MTOT (AANCH*HDIM*WDIM)   // 600000
#define KTOP 1000
#define POSTN 300
#define NBINS 16384
#define CAND_CAP 4096
#define NWORDS 16                // ceil(1000/64)
#define NMS_TH 0.7f
#define BPB 75                   // blocks per batch for hist
#define CHUNK (MTOT/BPB)         // 8000, divisible by 4

// ---------------- ws layout ----------------
constexpr size_t OFF_HIST = 0;
constexpr size_t SZ_HIST  = (size_t)NBATCH*NBINS*4;                 // 262144
constexpr size_t OFF_CNT  = OFF_HIST + SZ_HIST;
constexpr size_t OFF_THR  = OFF_CNT + 256;
constexpr size_t OFF_CAND = OFF_THR + 256;
constexpr size_t OFF_TOPK = OFF_CAND + (size_t)NBATCH*CAND_CAP*8;
constexpr size_t OFF_PROP = OFF_TOPK + (size_t)NBATCH*KTOP*8;
constexpr size_t OFF_SCORE= OFF_PROP + (size_t)NBATCH*KTOP*5*4;
constexpr size_t OFF_CORN = OFF_SCORE+ (size_t)NBATCH*KTOP*4;
constexpr size_t OFF_AREA = OFF_CORN + (size_t)NBATCH*KTOP*8*4;
constexpr size_t OFF_RAD  = OFF_AREA + (size_t)NBATCH*KTOP*4;
constexpr size_t OFF_VALID= OFF_RAD  + (size_t)NBATCH*KTOP*4;
constexpr size_t OFF_MASK = OFF_VALID+ (size_t)NBATCH*KTOP*4;
constexpr size_t OFF_KEEP = OFF_MASK + (size_t)NBATCH*KTOP*NWORDS*8;

__device__ __forceinline__ float sigmoid_ref(float x) {
  return 1.0f / (1.0f + expf(-x));
}

// ---------------- histogram: LDS-privatized ----------------
__global__ __launch_bounds__(256) void k_hist(const float* __restrict__ obj,
                                              uint32_t* __restrict__ hist) {
  __shared__ uint32_t h[NBINS];
  for (int i = threadIdx.x; i < NBINS; i += 256) h[i] = 0;
  __syncthreads();
  int n = blockIdx.x / BPB, c = blockIdx.x % BPB;
  const float4* p = (const float4*)(obj + (size_t)n*MTOT + (size_t)c*CHUNK);
  const int nq = CHUNK/4;  // 2000
  for (int q = threadIdx.x; q < nq; q += 256) {
    float4 v = p[q];
    #pragma unroll
    for (int k = 0; k < 4; ++k) {
      float x = (&v.x)[k];
      uint32_t bits = __float_as_uint(sigmoid_ref(x));
      uint32_t bin = bits >> 16; if (bin > NBINS-1) bin = NBINS-1;
      atomicAdd(&h[bin], 1u);
    }
  }
  __syncthreads();
  for (int i = threadIdx.x; i < NBINS; i += 256) {
    uint32_t v = h[i];
    if (v) atomicAdd(&hist[n*NBINS + i], v);
  }
}

// ---------------- threshold: parallel partial sums ----------------
__global__ __launch_bounds__(256) void k_thresh(const uint32_t* __restrict__ hist,
                                                uint32_t* __restrict__ thr) {
  __shared__ uint32_t ps[256];
  int n = blockIdx.x, tid = threadIdx.x;
  uint32_t s = 0;
  const uint32_t* hb = &hist[n*NBINS];
  #pragma unroll 4
  for (int b = tid*64; b < tid*64+64; ++b) s += hb[b];
  ps[tid] = s;
  __syncthreads();
  if (tid == 0) {
    uint32_t cum = 0; int cidx = -1;
    for (int cc = 255; cc >= 0; --cc) {
      if (cum + ps[cc] >= KTOP) { cidx = cc; break; }
      cum += ps[cc];
    }
    if (cidx < 0) { thr[n] = 0u; return; }
    int b = cidx*64+63;
    for (; b >= cidx*64; --b) { cum += hb[b]; if (cum >= KTOP) break; }
    thr[n] = (uint32_t)(b < 0 ? 0 : b);
  }
}

// ---------------- compact candidates >= threshold bin ----------------
__global__ __launch_bounds__(256) void k_compact(const float* __restrict__ obj,
                                                 const uint32_t* __restrict__ thr,
                                                 uint64_t* __restrict__ cand,
                                                 uint32_t* __restrict__ cnt) {
  int t = blockIdx.x*blockDim.x + threadIdx.x;
  if (t >= NBATCH*MTOT) return;
  int n = t / MTOT;
  int rem = t % MTOT;
  float x = obj[t];
  uint32_t bits = __float_as_uint(sigmoid_ref(x));
  uint32_t bin = bits >> 16; if (bin > NBINS-1) bin = NBINS-1;
  if (bin >= thr[n]) {
    int hw = rem % (HDIM*WDIM);
    int a  = rem / (HDIM*WDIM);
    uint32_t fidx = (uint32_t)(hw*AANCH + a);
    uint32_t p = atomicAdd(&cnt[n], 1u);
    if (p < CAND_CAP)
      cand[(size_t)n*CAND_CAP + p] = ((uint64_t)bits << 32) | (uint32_t)(~fidx);
  }
}

// ---------------- one block per batch: bitonic sort, emit top KTOP ----------------
__global__ __launch_bounds__(1024) void k_sort(const uint64_t* __restrict__ cand,
                                               const uint32_t* __restrict__ cnt,
                                               uint64_t* __restrict__ topk) {
  __shared__ uint64_t sk[CAND_CAP];
  int n = blockIdx.x, tid = threadIdx.x;
  uint32_t c = cnt[n]; if (c > CAND_CAP) c = CAND_CAP;
  for (int i = tid; i < CAND_CAP; i += 1024)
    sk[i] = (i < (int)c) ? cand[(size_t)n*CAND_CAP + i] : 0ull;
  __syncthreads();
  for (int len = 2; len <= CAND_CAP; len <<= 1) {
    for (int str = len >> 1; str > 0; str >>= 1) {
      for (int i = tid; i < CAND_CAP; i += 1024) {
        int j = i ^ str;
        if (j > i) {
          bool up = ((i & len) == 0);
          uint64_t x = sk[i], y = sk[j];
          if ((x > y) == up) { sk[i] = y; sk[j] = x; }
        }
      }
      __syncthreads();
    }
  }
  for (int k = tid; k < KTOP; k += 1024)
    topk[(size_t)n*KTOP + k] = sk[CAND_CAP-1-k];
}

// ---------------- decode + corners + quick-reject metadata ----------------
__global__ void k_decode(const float* __restrict__ breg, const float* __restrict__ anch,
                         const uint64_t* __restrict__ topk,
                         float* __restrict__ prop, float* __restrict__ score,
                         float* __restrict__ corn, float* __restrict__ area,
                         float* __restrict__ rad, uint32_t* __restrict__ validf) {
#pragma clang fp contract(off)
  int t = blockIdx.x*blockDim.x + threadIdx.x;
  if (t >= NBATCH*KTOP) return;
  int n = t / KTOP;
  uint64_t key = topk[t];
  uint32_t idx = ~(uint32_t)(key & 0xFFFFFFFFull);
  float s = __uint_as_float((uint32_t)(key >> 32));
  int a = idx % AANCH, pos = idx / AANCH;
  int w = pos % WDIM, h = pos / WDIM;
  float d[5], an[5];
  #pragma unroll
  for (int j = 0; j < 5; ++j)
    d[j] = breg[((n*(AANCH*5) + (a*5+j))*HDIM + h)*WDIM + w];
  #pragma unroll
  for (int j = 0; j < 5; ++j)
    an[j] = anch[((size_t)n*MTOT + idx)*5 + j];
  const float CLIP = 4.135166556742356f;           // log(1000/16)
  float dw = fminf(d[2], CLIP), dh = fminf(d[3], CLIP);
  float x  = d[0]*an[2] + an[0];
  float y  = d[1]*an[3] + an[1];
  float bw = expf(dw)*an[2];
  float bh = expf(dh)*an[3];
  float th = an[4] + d[4]*57.29577951308232f;      // 180/pi
  prop[t*5+0]=x; prop[t*5+1]=y; prop[t*5+2]=bw; prop[t*5+3]=bh; prop[t*5+4]=th;
  score[t] = s;
  validf[t] = (bw >= 4.0f && bh >= 4.0f) ? 1u : 0u;
  area[t] = bw*bh;
  rad[t]  = 0.5f*sqrtf(bw*bw + bh*bh);
  float ang = th * 0.017453292519943295f;          // pi/180
  float cs = cosf(ang), sn = sinf(ang);
  float hw2 = bw*0.5f, hh2 = bh*0.5f;
  const float sx[4] = {1.f,-1.f,-1.f,1.f};
  const float sy[4] = {1.f,1.f,-1.f,-1.f};
  #pragma unroll
  for (int k = 0; k < 4; ++k) {
    float dxk = sx[k]*hw2, dyk = sy[k]*hh2;
    float cx = (x + cs*dxk) - sn*dyk;
    float cy = (y + sn*dxk) + cs*dyk;
    corn[t*8 + k*2 + 0] = cx;
    corn[t*8 + k*2 + 1] = cy;
  }
}

// ---------------- Sutherland-Hodgman (mirrors reference arithmetic) ----------------
__device__ float quad_inter_area(const float* __restrict__ ca, const float* __restrict__ cb) {
#pragma clang fp contract(off)
  float px[8], py[8];
  int n = 4;
  #pragma unroll
  for (int i = 0; i < 4; ++i) { px[i] = ca[2*i]; py[i] = ca[2*i+1]; }
  for (int e = 0; e < 4; ++e) {
    float p1x = cb[2*e], p1y = cb[2*e+1];
    int e2 = (e+1)&3;
    float dx = cb[2*e2] - p1x, dy = cb[2*e2+1] - p1y;
    float sd[8];
    for (int i = 0; i < n; ++i)
      sd[i] = dx*(py[i]-p1y) - dy*(px[i]-p1x);
    float qx[8], qy[8];
    int m = 0;
    for (int i = 0; i < n; ++i) {
      int nx = (i+1 < n) ? i+1 : 0;
      bool ini = sd[i] >= 0.0f, inn = sd[nx] >= 0.0f;
      if (ini) { qx[m]=px[i]; qy[m]=py[i]; ++m; }
      if (ini != inn) {
        float den = sd[i]-sd[nx];
        float dd = (fabsf(den) < 1e-12f) ? 1e-12f : den;
        float tt = sd[i]/dd;
        qx[m] = px[i] + tt*(px[nx]-px[i]);
        qy[m] = py[i] + tt*(py[nx]-py[i]);
        ++m;
      }
    }
    n = m;
    for (int i = 0; i < n; ++i) { px[i]=qx[i]; py[i]=qy[i]; }
    if (n == 0) break;
  }
  float ssum = 0.0f;
  for (int i = 0; i < n; ++i) {
    int nx = (i+1 < n) ? i+1 : 0;
    ssum += px[i]*py[nx] - px[nx]*py[i];
  }
  return 0.5f*fabsf(ssum);
}

// ---------------- suppression bitmask: one wave per (n, i, jb) ----------------
__global__ __launch_bounds__(256) void k_mask(const float* __restrict__ prop,
                                              const float* __restrict__ corn,
                                              const float* __restrict__ area,
                                              const float* __restrict__ rad,
                                              uint64_t* __restrict__ mask) {
#pragma clang fp contract(off)
  int gw = blockIdx.x*(blockDim.x>>6) + (threadIdx.x>>6);
  int lane = threadIdx.x & 63;
  if (gw >= NBATCH*KTOP*NWORDS) return;
  int n   = gw / (KTOP*NWORDS);
  int rem = gw % (KTOP*NWORDS);
  int i   = rem / NWORDS;
  int jb  = rem % NWORDS;
  int j   = jb*64 + lane;
  bool sup = false;
  if (j > i && j < KTOP) {
    int bi = n*KTOP + i, bj = n*KTOP + j;
    float dx = prop[bi*5+0] - prop[bj*5+0];
    float dy = prop[bi*5+1] - prop[bj*5+1];
    float d2 = dx*dx + dy*dy;
    float rs = rad[bi] + rad[bj];
    if (d2 <= rs*rs*1.0001f) {
      float inter = quad_inter_area(&corn[(size_t)bi*8], &corn[(size_t)bj*8]);
      float uni = (area[bi] + area[bj]) - inter;
      float iou = inter / fmaxf(uni, 1e-8f);
      sup = iou > NMS_TH;
    }
  }
  unsigned long long w64 = __ballot(sup);
  if (lane == 0) mask[((size_t)n*KTOP + i)*NWORDS + jb] = w64;
}

// ---------------- greedy NMS, mask preloaded into LDS ----------------
__global__ __launch_bounds__(64) void k_nms(const uint32_t* __restrict__ validf,
                                            const uint64_t* __restrict__ mask,
                                            uint64_t* __restrict__ keep) {
  __shared__ uint64_t sm[KTOP*NWORDS];   // 128000 B
  __shared__ uint64_t kw[NWORDS];
  int n = blockIdx.x, lane = threadIdx.x;
  const uint64_t* src = &mask[(size_t)n*KTOP*NWORDS];
  for (int i = lane; i < KTOP*NWORDS; i += 64) sm[i] = src[i];
  if (lane < NWORDS) {
    uint64_t wrd = 0;
    for (int b = 0; b < 64; ++b) {
      int k = lane*64 + b;
      if (k < KTOP && validf[n*KTOP + k]) wrd |= (1ull << b);
    }
    kw[lane] = wrd;
  }
  __syncthreads();
  for (int i = 0; i < KTOP; ++i) {
    bool alive = (kw[i>>6] >> (i&63)) & 1ull;
    if (alive && lane < NWORDS) kw[lane] &= ~sm[i*NWORDS + lane];
    __syncthreads();
  }
  if (lane == 0) {
    int prev = 0;
    for (int t = 0; t < NWORDS; ++t) {
      uint64_t wrd = kw[t];
      int pc = __popcll(wrd);
      if (prev >= POSTN) wrd = 0;
      else if (prev + pc > POSTN) {
        int allow = POSTN - prev;
        while (__popcll(wrd) > allow) wrd &= ~(1ull << (63 - __clzll(wrd)));
      }
      prev += __popcll(wrd);
      keep[n*NWORDS + t] = wrd;
    }
  }
}

__global__ void k_out(const float* __restrict__ prop, const float* __restrict__ score,
                      const uint64_t* __restrict__ keep, float* __restrict__ out) {
  int t = blockIdx.x*blockDim.x + threadIdx.x;
  if (t >= NBATCH*KTOP) return;
  int n = t / KTOP, k = t % KTOP;
  bool b = (keep[n*NWORDS + (k>>6)] >> (k&63)) & 1ull;
  float f = b ? 1.0f : 0.0f;
  #pragma unroll
  for (int c = 0; c < 5; ++c) out[t*6 + c] = prop[t*5 + c] * f;
  out[t*6 + 5] = score[t] * f;
}

extern "C" void kernel_launch(void* const* d_in, const int* in_sizes, int n_in,
                              void* d_out, int out_size, void* d_ws, size_t ws_size,
                              hipStream_t stream) {
  const float* obj  = (const float*)d_in[0];
  const float* breg = (const float*)d_in[1];
  const float* anch = (const float*)d_in[2];
  float* out = (float*)d_out;
  char* ws = (char*)d_ws;

  uint32_t* hist  = (uint32_t*)(ws + OFF_HIST);
  uint32_t* cnt   = (uint32_t*)(ws + OFF_CNT);
  uint32_t* thr   = (uint32_t*)(ws + OFF_THR);
  uint64_t* cand  = (uint64_t*)(ws + OFF_CAND);
  uint64_t* topk  = (uint64_t*)(ws + OFF_TOPK);
  float*    prop  = (float*)(ws + OFF_PROP);
  float*    score = (float*)(ws + OFF_SCORE);
  float*    corn  = (float*)(ws + OFF_CORN);
  float*    area  = (float*)(ws + OFF_AREA);
  float*    rad   = (float*)(ws + OFF_RAD);
  uint32_t* validf= (uint32_t*)(ws + OFF_VALID);
  uint64_t* mask  = (uint64_t*)(ws + OFF_MASK);
  uint64_t* keep  = (uint64_t*)(ws + OFF_KEEP);

  hipMemsetAsync(ws, 0, OFF_THR, stream);   // zero hist + cand counters

  int nt = NBATCH*MTOT;
  k_hist   <<<NBATCH*BPB, 256, 0, stream>>>(obj, hist);
  k_thresh <<<NBATCH, 256, 0, stream>>>(hist, thr);
  k_compact<<<(nt+255)/256, 256, 0, stream>>>(obj, thr, cand, cnt);
  k_sort   <<<NBATCH, 1024, 0, stream>>>(cand, cnt, topk);
  k_decode <<<(NBATCH*KTOP+255)/256, 256, 0, stream>>>(breg, anch, topk, prop, score, corn, area, rad, validf);
  k_mask   <<<NBATCH*KTOP*NWORDS/4, 256, 0, stream>>>(prop, corn, area, rad, mask);
  k_nms    <<<NBATCH, 64, 0, stream>>>(validf, mask, keep);
  k_out    <<<(NBATCH*KTOP+255)/256, 256, 0, stream>>>(prop, score, keep, out);
}